// Round 9
// baseline (1248.595 us; speedup 1.0000x reference)
//
#include <hip/hip_runtime.h>
#include <hip/hip_bf16.h>

// Bucket-sorted aggregation (64 nodes/bucket), Wh folded forward:
//   S = hidden @ Ws.T, R = rela @ Wr.T, Q[b] = rela[q_rel[b]] @ Wqr.T + bqr
//   H' = hidden @ Wh.T, R' = rela @ Wh.T
//   hist: counts[obj>>6]++        (1563 line-padded counters -> tiny frontier)
//   bscan: exclusive scan of 1563 bucket counts (single small block)
//   alpha+scatter: rec[cur[bucket]++] = {alpha, sub | rel<<17 | (obj&63)<<26}
//   bucket_reduce: one WG per bucket, LDS 64x68 f32 accumulate (ds f32 atomics),
//                  dense row writes of H'/R' combination directly into d_out

typedef int v2i __attribute__((ext_vector_type(2)));

#define BSH 6                 // 64 nodes per bucket
#define BNODES (1 << BSH)
#define ROWP 68               // padded LDS row stride (floats): 68%32=4 -> banks shift per row
#define CPAD 16               // cursor padding (ints) -> one 64B line per counter

__global__ void proj32_kernel(const float* __restrict__ X, const float* __restrict__ W,
                              float* __restrict__ out, int nrows) {
    // out[n][k] = sum_d X[n][d] * W[k][d],  k<32, d<64
    __shared__ float wT[64 * 32];
    int tid = threadIdx.x;
    for (int i = tid; i < 32 * 64; i += 256) {
        int k = i >> 6, d = i & 63;
        wT[d * 32 + k] = W[i];
    }
    __syncthreads();
    int row = blockIdx.x * 8 + (tid >> 5);
    int k = tid & 31;
    if (row >= nrows) return;
    const float4* X4 = (const float4*)(X + (size_t)row * 64);
    float acc = 0.f;
#pragma unroll
    for (int d4 = 0; d4 < 16; ++d4) {
        float4 x = X4[d4];
        int d = d4 * 4;
        acc += x.x * wT[(d + 0) * 32 + k] + x.y * wT[(d + 1) * 32 + k]
             + x.z * wT[(d + 2) * 32 + k] + x.w * wT[(d + 3) * 32 + k];
    }
    out[(size_t)row * 32 + k] = acc;
}

// out[n][j] = sum_d X[n][d] * W[j][d]  (64x64), out-of-place row stream
__global__ void proj64_kernel(const float* __restrict__ X, const float* __restrict__ W,
                              float* __restrict__ out, int nrows) {
    __shared__ float wT[64 * 64];   // wT[d*64+j] = W[j*64+d]
    int tid = threadIdx.x;
    for (int i = tid; i < 64 * 64; i += 256) {
        int j = i >> 6, d = i & 63;
        wT[d * 64 + j] = W[i];
    }
    __syncthreads();
    int wave = tid >> 6, j = tid & 63;
    int base = blockIdx.x * 32;
    for (int r = wave; r < 32; r += 4) {
        int row = base + r;
        if (row >= nrows) break;
        const float4* rp = (const float4*)(X + (size_t)row * 64);
        float acc = 0.f;
#pragma unroll
        for (int d4 = 0; d4 < 16; ++d4) {
            float4 m4 = rp[d4];
            int d = d4 * 4;
            acc += m4.x * wT[(d + 0) * 64 + j] + m4.y * wT[(d + 1) * 64 + j]
                 + m4.z * wT[(d + 2) * 64 + j] + m4.w * wT[(d + 3) * 64 + j];
        }
        out[(size_t)row * 64 + j] = acc;
    }
}

__global__ void qproj_kernel(const int* __restrict__ q_rel, const float* __restrict__ rela,
                             const float* __restrict__ Wqr, const float* __restrict__ bqr,
                             float* __restrict__ Q, int batch) {
    int tid = threadIdx.x;
    int b = tid >> 5, k = tid & 31;
    if (b >= batch) return;
    int qr = q_rel[b];
    const float* x = rela + (size_t)qr * 64;
    const float* w = Wqr + (size_t)k * 64;
    float acc = bqr[k];
    for (int d = 0; d < 64; ++d) acc += w[d] * x[d];
    Q[b * 32 + k] = acc;
}

// one thread per edge: bucket histogram (counters line-padded)
__global__ void hist_kernel(const int* __restrict__ edges, int* __restrict__ counts,
                            int n_edge) {
    int e = blockIdx.x * 256 + threadIdx.x;
    if (e >= n_edge) return;
    int obj = edges[(size_t)e * 6 + 5];
    atomicAdd(&counts[(obj >> BSH) * CPAD], 1);
}

// single small block: exclusive scan over NB bucket counts -> offs (dense), cur (padded)
__global__ void bscan_kernel(const int* __restrict__ counts, int* __restrict__ offs,
                             int* __restrict__ cur, int NB) {
    __shared__ int s[256];
    __shared__ int carry_s;
    int tid = threadIdx.x;
    if (tid == 0) carry_s = 0;
    __syncthreads();
    for (int base = 0; base < NB; base += 256) {
        int idx = base + tid;
        int v = (idx < NB) ? counts[idx * CPAD] : 0;
        s[tid] = v;
        __syncthreads();
        for (int off = 1; off < 256; off <<= 1) {
            int t = (tid >= off) ? s[tid - off] : 0;
            __syncthreads();
            s[tid] += t;
            __syncthreads();
        }
        int excl = carry_s + s[tid] - v;
        if (idx < NB) { offs[idx] = excl; cur[idx * CPAD] = excl; }
        __syncthreads();
        if (tid == 0) carry_s += s[255];
        __syncthreads();
    }
    if (tid == 0) offs[NB] = carry_s;
}

// 16 lanes per edge: compute alpha and scatter the record (bucket cursors).
__global__ void alpha_scatter_kernel(const int* __restrict__ edges,
                                     const float2* __restrict__ S2,
                                     const float2* __restrict__ R2,
                                     const float2* __restrict__ Q2,
                                     const float2* __restrict__ w2,
                                     const float* __restrict__ w_alpha_b,
                                     int* __restrict__ cur, float2* __restrict__ rec,
                                     int n_edge) {
    int tid = threadIdx.x;
    int lane = tid & 15;
    int e = blockIdx.x * 16 + (tid >> 4);
    if (e >= n_edge) return;
    const int2* er = (const int2*)(edges + (size_t)e * 6);
    int ridx = er[0].x;
    int rel  = er[1].x;
    int2 e45 = er[2];   // {sub, obj}
    int sub  = e45.x;
    int obj  = e45.y;
    float2 s = S2[(size_t)sub * 16 + lane];
    float2 r = R2[(size_t)rel * 16 + lane];
    float2 q = Q2[ridx * 16 + lane];
    float a0 = fmaxf(s.x + r.x + q.x, 0.f);
    float a1 = fmaxf(s.y + r.y + q.y, 0.f);
    float2 w = w2[lane];
    float p = a0 * w.x + a1 * w.y;
#pragma unroll
    for (int off = 8; off > 0; off >>= 1) p += __shfl_xor(p, off, 16);
    if (lane == 0) {
        float alpha = 1.f / (1.f + __expf(-(p + w_alpha_b[0])));
        int pos = atomicAdd(&cur[(obj >> BSH) * CPAD], 1);
        float2 out;
        out.x = alpha;
        // sub:17 | rel:9 | objlow:6  == 32 bits exactly
        out.y = __int_as_float(sub | (rel << 17) | ((obj & (BNODES - 1)) << 26));
        rec[pos] = out;
    }
}

// one workgroup per bucket: LDS-accumulate 64 node rows, write densely.
__global__ void bucket_reduce_kernel(const float2* __restrict__ rec,
                                     const int* __restrict__ offs,
                                     const float4* __restrict__ T4,  // H' (or hidden)
                                     const float4* __restrict__ U4,  // R' (or rela)
                                     float4* __restrict__ out4, int n_node) {
    __shared__ float acc[BNODES * ROWP];
    int tid = threadIdx.x;
    int b = blockIdx.x;
    for (int i = tid; i < BNODES * ROWP; i += 256) acc[i] = 0.f;
    __syncthreads();
    int start = offs[b], end = offs[b + 1];
    int group = tid >> 4;   // 16 record-groups per block
    int t = tid & 15;       // dim-quad index
    for (int i = start + group; i < end; i += 16) {
        float2 r = rec[i];                      // same addr across the 16-lane group
        float a = r.x;
        int pk = __float_as_int(r.y);
        int sub = pk & 0x1FFFF;
        int rel = (pk >> 17) & 0x1FF;
        int nl = ((unsigned)pk) >> 26;
        float4 h = T4[(size_t)sub * 16 + t];
        float4 u = U4[(size_t)rel * 16 + t];
        float* dst = &acc[nl * ROWP + t * 4];
        atomicAdd(dst + 0, a * (h.x + u.x));    // ds f32 atomics (LDS)
        atomicAdd(dst + 1, a * (h.y + u.y));
        atomicAdd(dst + 2, a * (h.z + u.z));
        atomicAdd(dst + 3, a * (h.w + u.w));
    }
    __syncthreads();
    int base_node = b << BSH;
#pragma unroll
    for (int q = 0; q < 4; ++q) {
        int idx = q * 256 + tid;                // 0..1023 = 64 rows x 16 quads
        int nl = idx >> 4, tt = idx & 15;
        int node = base_node + nl;
        if (node < n_node)
            out4[(size_t)node * 16 + tt] = *(float4*)&acc[nl * ROWP + tt * 4];
    }
}

// fallback path only: in-place io rows <- io rows @ Wh.T
__global__ void outgemm_inplace_kernel(const float* __restrict__ Wh, float* __restrict__ io,
                                       int n_node) {
    __shared__ float wT[64 * 64];
    int tid = threadIdx.x;
    for (int i = tid; i < 64 * 64; i += 256) {
        int j = i >> 6, d = i & 63;
        wT[d * 64 + j] = Wh[i];
    }
    __syncthreads();
    int wave = tid >> 6, j = tid & 63;
    int base = blockIdx.x * 32;
    for (int r = wave; r < 32; r += 4) {
        int row = base + r;
        if (row >= n_node) break;
        const float4* rp = (const float4*)(io + (size_t)row * 64);
        float acc = 0.f;
#pragma unroll
        for (int d4 = 0; d4 < 16; ++d4) {
            float4 m4 = rp[d4];
            int d = d4 * 4;
            acc += m4.x * wT[(d + 0) * 64 + j] + m4.y * wT[(d + 1) * 64 + j]
                 + m4.z * wT[(d + 2) * 64 + j] + m4.w * wT[(d + 3) * 64 + j];
        }
        io[(size_t)row * 64 + j] = acc;
    }
}

extern "C" void kernel_launch(void* const* d_in, const int* in_sizes, int n_in,
                              void* d_out, int out_size, void* d_ws, size_t ws_size,
                              hipStream_t stream) {
    const int*   q_rel     = (const int*)d_in[1];
    const float* hidden    = (const float*)d_in[2];
    const int*   edges     = (const int*)d_in[3];
    const float* rela      = (const float*)d_in[7];
    const float* Ws        = (const float*)d_in[8];
    const float* Wr        = (const float*)d_in[9];
    const float* Wqr       = (const float*)d_in[10];
    const float* bqr       = (const float*)d_in[11];
    const float* w_alpha_w = (const float*)d_in[12];
    const float* w_alpha_b = (const float*)d_in[13];
    const float* Wh        = (const float*)d_in[14];

    int n_node = in_sizes[2] / 64;
    int n_edge = in_sizes[3] / 6;
    int n_rel  = in_sizes[7] / 64;
    int batch  = in_sizes[1];

    int nbuck = (n_node + BNODES - 1) >> BSH;

    // workspace layout (~55 MB with fold)
    float* S      = (float*)d_ws;                         // n_node*32
    float* R      = S + (size_t)n_node * 32;              // n_rel*32
    float* Q      = R + (size_t)n_rel * 32;               // batch*32
    int*   counts = (int*)(Q + (size_t)batch * 32);       // nbuck*CPAD
    int*   offs   = counts + (size_t)nbuck * CPAD;        // nbuck+1
    int*   cur    = offs + nbuck + 1;                     // nbuck*CPAD
    size_t rec_off = (size_t)(cur + (size_t)nbuck * CPAD - (int*)d_ws);
    rec_off = (rec_off + 3) & ~(size_t)3;                 // align 16B
    float2* rec   = (float2*)((int*)d_ws + rec_off);      // n_edge float2
    float* Hp     = (float*)(rec + n_edge);               // n_node*64 (fold path)
    float* Rp     = Hp + (size_t)n_node * 64;             // n_rel*64
    size_t need   = (size_t)((char*)(Rp + (size_t)n_rel * 64) - (char*)d_ws);
    bool fold = (ws_size >= need);   // ws_size constant across calls -> stable branch

    (void)hipMemsetAsync(counts, 0, (size_t)nbuck * CPAD * sizeof(int), stream);

    proj32_kernel<<<(n_node + 7) / 8, 256, 0, stream>>>(hidden, Ws, S, n_node);
    proj32_kernel<<<(n_rel + 7) / 8, 256, 0, stream>>>(rela, Wr, R, n_rel);
    qproj_kernel<<<1, 256, 0, stream>>>(q_rel, rela, Wqr, bqr, Q, batch);
    if (fold) {
        proj64_kernel<<<(n_node + 31) / 32, 256, 0, stream>>>(hidden, Wh, Hp, n_node);
        proj64_kernel<<<(n_rel + 31) / 32, 256, 0, stream>>>(rela, Wh, Rp, n_rel);
    }

    hist_kernel<<<(n_edge + 255) / 256, 256, 0, stream>>>(edges, counts, n_edge);
    bscan_kernel<<<1, 256, 0, stream>>>(counts, offs, cur, nbuck);

    alpha_scatter_kernel<<<(n_edge + 15) / 16, 256, 0, stream>>>(
        edges, (const float2*)S, (const float2*)R, (const float2*)Q,
        (const float2*)w_alpha_w, w_alpha_b, cur, rec, n_edge);

    if (fold) {
        bucket_reduce_kernel<<<nbuck, 256, 0, stream>>>(
            rec, offs, (const float4*)Hp, (const float4*)Rp, (float4*)d_out, n_node);
    } else {
        bucket_reduce_kernel<<<nbuck, 256, 0, stream>>>(
            rec, offs, (const float4*)hidden, (const float4*)rela, (float4*)d_out, n_node);
        outgemm_inplace_kernel<<<(n_node + 31) / 32, 256, 0, stream>>>(Wh, (float*)d_out, n_node);
    }
}

// Round 10
// 536.636 us; speedup vs baseline: 2.3267x; 2.3267x over previous
//
#include <hip/hip_runtime.h>
#include <hip/hip_bf16.h>

// Atomic-free aggregation via per-node counting sort (R6 structure) + packed edges:
//   S = hidden @ Ws.T, R = rela @ Wr.T, Q[b] = rela[q_rel[b]] @ Wqr.T + bqr
//   hist+pack: counts[obj]++; pk2[e] = {sub|rel<<17, obj|ridx<<20}  (dense 8B)
//   multi-block exclusive scan -> offs/cur
//   alpha+scatter: alpha = sigmoid(...); rec[cur[obj]++] = {alpha, sub|rel<<17}
//   reduce: one wave per node, 4 records in flight, float4 gathers -> d_out (agg)
//   outgemm_inplace: d_out rows <- d_out rows @ Wh.T

__global__ void proj32_kernel(const float* __restrict__ X, const float* __restrict__ W,
                              float* __restrict__ out, int nrows) {
    // out[n][k] = sum_d X[n][d] * W[k][d],  k<32, d<64
    __shared__ float wT[64 * 32];
    int tid = threadIdx.x;
    for (int i = tid; i < 32 * 64; i += 256) {
        int k = i >> 6, d = i & 63;
        wT[d * 32 + k] = W[i];
    }
    __syncthreads();
    int row = blockIdx.x * 8 + (tid >> 5);
    int k = tid & 31;
    if (row >= nrows) return;
    const float4* X4 = (const float4*)(X + (size_t)row * 64);
    float acc = 0.f;
#pragma unroll
    for (int d4 = 0; d4 < 16; ++d4) {
        float4 x = X4[d4];
        int d = d4 * 4;
        acc += x.x * wT[(d + 0) * 32 + k] + x.y * wT[(d + 1) * 32 + k]
             + x.z * wT[(d + 2) * 32 + k] + x.w * wT[(d + 3) * 32 + k];
    }
    out[(size_t)row * 32 + k] = acc;
}

__global__ void qproj_kernel(const int* __restrict__ q_rel, const float* __restrict__ rela,
                             const float* __restrict__ Wqr, const float* __restrict__ bqr,
                             float* __restrict__ Q, int batch) {
    int tid = threadIdx.x;
    int b = tid >> 5, k = tid & 31;
    if (b >= batch) return;
    int qr = q_rel[b];
    const float* x = rela + (size_t)qr * 64;
    const float* w = Wqr + (size_t)k * 64;
    float acc = bqr[k];
    for (int d = 0; d < 64; ++d) acc += w[d] * x[d];
    Q[b * 32 + k] = acc;
}

// one thread per edge: histogram of obj AND pack edge fields into dense 8B records.
// pk.x = sub | rel<<17   (sub<2^17, rel<2^9)
// pk.y = obj | ridx<<20  (obj<2^17, ridx<8)
__global__ void hist_pack_kernel(const int* __restrict__ edges, int* __restrict__ counts,
                                 int2* __restrict__ pk2, int n_edge) {
    int e = blockIdx.x * 256 + threadIdx.x;
    if (e >= n_edge) return;
    const int* ep = edges + (size_t)e * 6;
    int2 a01 = *(const int2*)ep;        // {r_idx, pad}
    int2 a23 = *(const int2*)(ep + 2);  // {rel, pad}
    int2 a45 = *(const int2*)(ep + 4);  // {sub, obj}
    atomicAdd(&counts[a45.y], 1);
    pk2[e] = make_int2(a45.x | (a23.x << 17), a45.y | (a01.x << 20));
}

// ---- multi-block exclusive scan (counts[0..N) -> offs[0..N], cur[0..N)) ----
#define SCAN_CHUNK 1024

__global__ void scan_partial_kernel(const int* __restrict__ counts, int* __restrict__ bsum,
                                    int N) {
    __shared__ int s[256];
    int base = blockIdx.x * SCAN_CHUNK;
    int tid = threadIdx.x;
    int sum = 0;
#pragma unroll
    for (int k = 0; k < 4; ++k) {
        int idx = base + k * 256 + tid;
        if (idx < N) sum += counts[idx];
    }
    s[tid] = sum;
    __syncthreads();
    for (int off = 128; off > 0; off >>= 1) {
        if (tid < off) s[tid] += s[tid + off];
        __syncthreads();
    }
    if (tid == 0) bsum[blockIdx.x] = s[0];
}

__global__ void scan_bsum_kernel(int* __restrict__ bsum, int* __restrict__ offs, int B, int N) {
    __shared__ int s[1024];
    int tid = threadIdx.x;
    int v = (tid < B) ? bsum[tid] : 0;
    s[tid] = v;
    __syncthreads();
    for (int off = 1; off < 1024; off <<= 1) {
        int t = (tid >= off) ? s[tid - off] : 0;
        __syncthreads();
        s[tid] += t;
        __syncthreads();
    }
    if (tid < B) bsum[tid] = s[tid] - v;   // exclusive block prefix
    if (tid == 0) offs[N] = s[1023];       // grand total
}

__global__ void scan_final_kernel(const int* __restrict__ counts, const int* __restrict__ bsum,
                                  int* __restrict__ offs, int* __restrict__ cur, int N) {
    __shared__ int s[256];
    int base = blockIdx.x * SCAN_CHUNK;
    int tid = threadIdx.x;
    int v[4];
    int sum = 0;
#pragma unroll
    for (int k = 0; k < 4; ++k) {
        int idx = base + tid * 4 + k;
        v[k] = (idx < N) ? counts[idx] : 0;
        sum += v[k];
    }
    s[tid] = sum;
    __syncthreads();
    for (int off = 1; off < 256; off <<= 1) {
        int t = (tid >= off) ? s[tid - off] : 0;
        __syncthreads();
        s[tid] += t;
        __syncthreads();
    }
    int run = bsum[blockIdx.x] + s[tid] - sum;
#pragma unroll
    for (int k = 0; k < 4; ++k) {
        int idx = base + tid * 4 + k;
        if (idx < N) { offs[idx] = run; cur[idx] = run; }
        run += v[k];
    }
}

// 16 lanes per edge: one packed header load, gather S/R/Q, scatter the record.
__global__ void alpha_scatter_kernel(const int2* __restrict__ pk2,
                                     const float2* __restrict__ S2,
                                     const float2* __restrict__ R2,
                                     const float2* __restrict__ Q2,
                                     const float2* __restrict__ w2,
                                     const float* __restrict__ w_alpha_b,
                                     int* __restrict__ cur, float2* __restrict__ rec,
                                     int n_edge) {
    int tid = threadIdx.x;
    int lane = tid & 15;
    int e = blockIdx.x * 16 + (tid >> 4);
    if (e >= n_edge) return;
    int2 h = pk2[e];                 // broadcast: same addr across the 16-lane group
    int sub  = h.x & 0x1FFFF;
    int rel  = h.x >> 17;            // bits 17..25, upper bits zero
    int obj  = h.y & 0x1FFFF;
    int ridx = h.y >> 20;
    float2 s = S2[(size_t)sub * 16 + lane];
    float2 r = R2[(size_t)rel * 16 + lane];
    float2 q = Q2[ridx * 16 + lane];
    float a0 = fmaxf(s.x + r.x + q.x, 0.f);
    float a1 = fmaxf(s.y + r.y + q.y, 0.f);
    float2 w = w2[lane];
    float p = a0 * w.x + a1 * w.y;
#pragma unroll
    for (int off = 8; off > 0; off >>= 1) p += __shfl_xor(p, off, 16);
    if (lane == 0) {
        float alpha = 1.f / (1.f + __expf(-(p + w_alpha_b[0])));
        int pos = atomicAdd(&cur[obj], 1);
        float2 out;
        out.x = alpha;
        out.y = __int_as_float(h.x);            // sub | rel<<17
        rec[pos] = out;
    }
}

// one 64-lane wave per node; 4 records in flight (groups of 16 lanes, float4 loads)
__global__ void reduce_kernel(const float2* __restrict__ rec, const int* __restrict__ offs,
                              const float4* __restrict__ hidden4,
                              const float4* __restrict__ rela4,
                              float4* __restrict__ out4, int n_node) {
    int lane = threadIdx.x & 63;
    int node = blockIdx.x * 4 + (threadIdx.x >> 6);
    if (node >= n_node) return;
    int g = lane >> 4;        // record subgroup 0..3
    int t = lane & 15;        // dim-quad index 0..15
    int start = offs[node], end = offs[node + 1];
    float4 acc = make_float4(0.f, 0.f, 0.f, 0.f);
    for (int i = start; i < end; i += 64) {
        int m = end - i;
        if (m > 64) m = 64;
        float a = 0.f;        // a=0 for idle lanes -> tail records contribute 0
        int pk = 0;
        if (lane < m) {
            float2 r = rec[i + lane];
            a = r.x;
            pk = __float_as_int(r.y);
        }
        for (int j = 0; 4 * j < m; ++j) {
            int src = 4 * j + g;
            float aj = __shfl(a, src, 64);
            int pkj = __shfl(pk, src, 64);
            int sub = pkj & 0x1FFFF, rel = pkj >> 17;
            float4 h = hidden4[(size_t)sub * 16 + t];
            float4 rr = rela4[(size_t)rel * 16 + t];
            acc.x += aj * (h.x + rr.x);
            acc.y += aj * (h.y + rr.y);
            acc.z += aj * (h.z + rr.z);
            acc.w += aj * (h.w + rr.w);
        }
    }
#pragma unroll
    for (int off = 16; off <= 32; off <<= 1) {
        acc.x += __shfl_xor(acc.x, off, 64);
        acc.y += __shfl_xor(acc.y, off, 64);
        acc.z += __shfl_xor(acc.z, off, 64);
        acc.w += __shfl_xor(acc.w, off, 64);
    }
    if (g == 0) out4[(size_t)node * 16 + t] = acc;
}

// in-place: io rows <- io rows @ Wh.T; rows streamed via wave-uniform float4 loads
__global__ void outgemm_inplace_kernel(const float* __restrict__ Wh, float* __restrict__ io,
                                       int n_node) {
    __shared__ float wT[64 * 64];   // wT[d*64+j] = Wh[j*64+d]
    int tid = threadIdx.x;
    for (int i = tid; i < 64 * 64; i += 256) {
        int j = i >> 6, d = i & 63;
        wT[d * 64 + j] = Wh[i];
    }
    __syncthreads();
    int wave = tid >> 6, j = tid & 63;
    int base = blockIdx.x * 32;              // 32 rows per block, 8 per wave
    for (int r = wave; r < 32; r += 4) {
        int row = base + r;
        if (row >= n_node) break;
        const float4* rp = (const float4*)(io + (size_t)row * 64);
        float acc = 0.f;
#pragma unroll
        for (int d4 = 0; d4 < 16; ++d4) {
            float4 m4 = rp[d4];              // wave-uniform broadcast load (L1)
            int d = d4 * 4;
            acc += m4.x * wT[(d + 0) * 64 + j] + m4.y * wT[(d + 1) * 64 + j]
                 + m4.z * wT[(d + 2) * 64 + j] + m4.w * wT[(d + 3) * 64 + j];
        }
        io[(size_t)row * 64 + j] = acc;      // same wave read the row fully first
    }
}

// fallback (ws too small for pk2): hist only
__global__ void hist_kernel(const int* __restrict__ edges, int* __restrict__ counts,
                            int n_edge) {
    int e = blockIdx.x * 256 + threadIdx.x;
    if (e >= n_edge) return;
    int obj = edges[(size_t)e * 6 + 5];
    atomicAdd(&counts[obj], 1);
}

// fallback scatter reading raw edges
__global__ void alpha_scatter_raw_kernel(const int* __restrict__ edges,
                                         const float2* __restrict__ S2,
                                         const float2* __restrict__ R2,
                                         const float2* __restrict__ Q2,
                                         const float2* __restrict__ w2,
                                         const float* __restrict__ w_alpha_b,
                                         int* __restrict__ cur, float2* __restrict__ rec,
                                         int n_edge) {
    int tid = threadIdx.x;
    int lane = tid & 15;
    int e = blockIdx.x * 16 + (tid >> 4);
    if (e >= n_edge) return;
    const int2* er = (const int2*)(edges + (size_t)e * 6);
    int ridx = er[0].x;
    int rel  = er[1].x;
    int2 e45 = er[2];
    int sub  = e45.x;
    int obj  = e45.y;
    float2 s = S2[(size_t)sub * 16 + lane];
    float2 r = R2[(size_t)rel * 16 + lane];
    float2 q = Q2[ridx * 16 + lane];
    float a0 = fmaxf(s.x + r.x + q.x, 0.f);
    float a1 = fmaxf(s.y + r.y + q.y, 0.f);
    float2 w = w2[lane];
    float p = a0 * w.x + a1 * w.y;
#pragma unroll
    for (int off = 8; off > 0; off >>= 1) p += __shfl_xor(p, off, 16);
    if (lane == 0) {
        float alpha = 1.f / (1.f + __expf(-(p + w_alpha_b[0])));
        int pos = atomicAdd(&cur[obj], 1);
        float2 out;
        out.x = alpha;
        out.y = __int_as_float(sub | (rel << 17));
        rec[pos] = out;
    }
}

extern "C" void kernel_launch(void* const* d_in, const int* in_sizes, int n_in,
                              void* d_out, int out_size, void* d_ws, size_t ws_size,
                              hipStream_t stream) {
    const int*   q_rel     = (const int*)d_in[1];
    const float* hidden    = (const float*)d_in[2];
    const int*   edges     = (const int*)d_in[3];
    const float* rela      = (const float*)d_in[7];
    const float* Ws        = (const float*)d_in[8];
    const float* Wr        = (const float*)d_in[9];
    const float* Wqr       = (const float*)d_in[10];
    const float* bqr       = (const float*)d_in[11];
    const float* w_alpha_w = (const float*)d_in[12];
    const float* w_alpha_b = (const float*)d_in[13];
    const float* Wh        = (const float*)d_in[14];

    int n_node = in_sizes[2] / 64;
    int n_edge = in_sizes[3] / 6;
    int n_rel  = in_sizes[7] / 64;
    int batch  = in_sizes[1];

    int n_sblk = (n_node + SCAN_CHUNK - 1) / SCAN_CHUNK;   // scan blocks (<=1024)

    // workspace layout (~47 MB with pk2)
    float* S      = (float*)d_ws;                         // n_node*32
    float* R      = S + (size_t)n_node * 32;              // n_rel*32
    float* Q      = R + (size_t)n_rel * 32;               // batch*32
    int*   counts = (int*)(Q + (size_t)batch * 32);       // n_node
    int*   offs   = counts + n_node;                      // n_node+1
    int*   cur    = offs + n_node + 1;                    // n_node
    int*   bsum   = cur + n_node;                         // n_sblk
    size_t rec_off = (size_t)(bsum + n_sblk - (int*)d_ws);
    rec_off = (rec_off + 3) & ~(size_t)3;                 // align 16B
    float2* rec   = (float2*)((int*)d_ws + rec_off);      // n_edge float2
    int2*  pk2    = (int2*)(rec + n_edge);                // n_edge int2
    size_t need   = (size_t)((char*)(pk2 + n_edge) - (char*)d_ws);
    bool packed = (ws_size >= need);   // ws_size constant across calls -> stable branch

    (void)hipMemsetAsync(counts, 0, (size_t)n_node * sizeof(int), stream);

    proj32_kernel<<<(n_node + 7) / 8, 256, 0, stream>>>(hidden, Ws, S, n_node);
    proj32_kernel<<<(n_rel + 7) / 8, 256, 0, stream>>>(rela, Wr, R, n_rel);
    qproj_kernel<<<1, 256, 0, stream>>>(q_rel, rela, Wqr, bqr, Q, batch);

    if (packed) {
        hist_pack_kernel<<<(n_edge + 255) / 256, 256, 0, stream>>>(edges, counts, pk2, n_edge);
    } else {
        hist_kernel<<<(n_edge + 255) / 256, 256, 0, stream>>>(edges, counts, n_edge);
    }

    scan_partial_kernel<<<n_sblk, 256, 0, stream>>>(counts, bsum, n_node);
    scan_bsum_kernel<<<1, 1024, 0, stream>>>(bsum, offs, n_sblk, n_node);
    scan_final_kernel<<<n_sblk, 256, 0, stream>>>(counts, bsum, offs, cur, n_node);

    if (packed) {
        alpha_scatter_kernel<<<(n_edge + 15) / 16, 256, 0, stream>>>(
            pk2, (const float2*)S, (const float2*)R, (const float2*)Q,
            (const float2*)w_alpha_w, w_alpha_b, cur, rec, n_edge);
    } else {
        alpha_scatter_raw_kernel<<<(n_edge + 15) / 16, 256, 0, stream>>>(
            edges, (const float2*)S, (const float2*)R, (const float2*)Q,
            (const float2*)w_alpha_w, w_alpha_b, cur, rec, n_edge);
    }

    reduce_kernel<<<(n_node + 3) / 4, 256, 0, stream>>>(
        rec, offs, (const float4*)hidden, (const float4*)rela, (float4*)d_out, n_node);
    outgemm_inplace_kernel<<<(n_node + 31) / 32, 256, 0, stream>>>(Wh, (float*)d_out, n_node);
}